// Round 3
// baseline (711.222 us; speedup 1.0000x reference)
//
#include <hip/hip_runtime.h>

#define N_NODES 100000
#define N_EDGES 800000
#define NF 81
#define NB 22
#define OC 64
#define SCAN_T 1024

// ---------------------------------------------------------------------------
// Node GEMM: outp[n,:] = feat[n,:81] @ w[:81,:64].
// Wave per node, lane = channel, weight column register-resident.
// CRITICAL: feat row loaded into fr[] in a separate batched loop (merges to
// s_load_dwordx16 batches -> ONE wait) before the fmac chain; R1/R2 fused
// load+fmac and paid ~81 serialized s_load round-trips per node (~175 us).
__global__ __launch_bounds__(256) void k_node(
    const float* __restrict__ feat, const float* __restrict__ w,
    float* __restrict__ outp, float4* __restrict__ xyz, int write_xyz)
{
    const int lane = threadIdx.x & 63;
    const int wid  = (int)((blockIdx.x * blockDim.x + threadIdx.x) >> 6);
    const int nw   = (int)((gridDim.x * blockDim.x) >> 6);

    float wc[NF];
#pragma unroll
    for (int k = 0; k < NF; ++k) wc[k] = w[k * OC + lane];

    for (int n0 = wid; n0 < N_NODES; n0 += nw) {
        const int n = __builtin_amdgcn_readfirstlane(n0);
        const float* f = feat + (long)n * NF;
        float fr[NF];
#pragma unroll
        for (int k = 0; k < NF; ++k) fr[k] = f[k];   // batched, single wait
        float a0 = 0.f, a1 = 0.f;                     // 2-way fmac ILP
#pragma unroll
        for (int k = 0; k + 1 < NF; k += 2) {
            a0 += fr[k] * wc[k];
            a1 += fr[k + 1] * wc[k + 1];
        }
        a0 += fr[NF - 1] * wc[NF - 1];
        outp[(long)n * OC + lane] = a0 + a1;
        if (write_xyz && lane == 0)
            xyz[n] = make_float4(fr[0], fr[1], fr[2], 0.f);
    }
}

// ---------------------------------------------------------------------------
// Counting sort of edges by src: hist -> scan -> scatter.
__global__ void k_hist(const int* __restrict__ src, int* __restrict__ cnt) {
    const int e = blockIdx.x * blockDim.x + threadIdx.x;
    if (e < N_EDGES) atomicAdd(&cnt[src[e]], 1);
}

__global__ void k_scan(const int* __restrict__ cnt, int* __restrict__ row,
                       int* __restrict__ cursor) {
    __shared__ int part[SCAN_T];
    const int t = threadIdx.x;
    const int CH = (N_NODES + SCAN_T - 1) / SCAN_T;          // 98
    const int lo = t * CH;
    const int hi = (lo + CH < N_NODES) ? lo + CH : N_NODES;
    int s = 0;
    for (int i = lo; i < hi; ++i) s += cnt[i];
    part[t] = s;
    __syncthreads();
    for (int off = 1; off < SCAN_T; off <<= 1) {             // inclusive scan
        int v = part[t];
        int add = (t >= off) ? part[t - off] : 0;
        __syncthreads();
        part[t] = v + add;
        __syncthreads();
    }
    int run = (t > 0) ? part[t - 1] : 0;                     // exclusive base
    for (int i = lo; i < hi; ++i) {
        const int c = cnt[i];
        row[i] = run;
        cursor[i] = run;
        run += c;
    }
    if (t == SCAN_T - 1) row[N_NODES] = run;                 // = N_EDGES
}

__global__ void k_scatter(const int* __restrict__ src, int* __restrict__ cursor,
                          int* __restrict__ sorted) {
    const int e = blockIdx.x * blockDim.x + threadIdx.x;
    if (e < N_EDGES) {
        const int pos = atomicAdd(&cursor[src[e]], 1);
        sorted[pos] = e;
    }
}

// ---------------------------------------------------------------------------
// Gather: wave per node, lane = channel. NO atomics — one plain RMW per node.
// contrib_e = inv_d2 * (PA[n] + PB[t]) + bond[e] @ w_n[81:103]
// PA[n] = PB[n] - (x*w0 + y*w1 + z*w2). Two edges per iteration: bond rows
// stay in SGPRs (2x22 = 44 SGPR, within the 102 budget) for v_fmac s,v.
__global__ __launch_bounds__(256) void k_gather(
    const int* __restrict__ row, const int* __restrict__ sorted,
    const int* __restrict__ dst, const float* __restrict__ bond,
    const float* __restrict__ w_n, const float* __restrict__ pb,
    const float4* __restrict__ xyz, float* __restrict__ out)
{
    const int lane = threadIdx.x & 63;
    const int wid  = (int)((blockIdx.x * blockDim.x + threadIdx.x) >> 6);
    if (wid >= N_NODES) return;
    const int n = __builtin_amdgcn_readfirstlane(wid);

    float wnb[NB];
#pragma unroll
    for (int j = 0; j < NB; ++j) wnb[j] = w_n[(NF + j) * OC + lane];
    const float w0 = w_n[0 * OC + lane];
    const float w1 = w_n[1 * OC + lane];
    const float w2 = w_n[2 * OC + lane];

    const int rs = row[n], re = row[n + 1];
    const float4 xs = xyz[n];
    const float pa = pb[(long)n * OC + lane]
                   - (xs.x * w0 + xs.y * w1 + xs.z * w2);

    float acc = 0.f;
    int i = rs;
    for (; i + 2 <= re; i += 2) {
        const int eA = sorted[i], eB = sorted[i + 1];
        const int tA = dst[eA],   tB = dst[eB];
        const float4 xtA = xyz[tA], xtB = xyz[tB];
        const float* bA = bond + (long)eA * NB;   // wave-uniform -> s_loads
        const float* bB = bond + (long)eB * NB;
        const float pbtA = pb[(long)tA * OC + lane];
        const float pbtB = pb[(long)tB * OC + lane];

        float dx = xs.x - xtA.x, dy = xs.y - xtA.y, dz = xs.z - xtA.z;
        const float d2A = dx * dx + dy * dy + dz * dz;
        dx = xs.x - xtB.x; dy = xs.y - xtB.y; dz = xs.z - xtB.z;
        const float d2B = dx * dx + dy * dy + dz * dz;
        const float invA = (d2A > 0.f) ? __builtin_amdgcn_rcpf(d2A) : 1.0e4f;
        const float invB = (d2B > 0.f) ? __builtin_amdgcn_rcpf(d2B) : 1.0e4f;

        acc += (pa + pbtA) * invA + (pa + pbtB) * invB;
#pragma unroll
        for (int j = 0; j < NB; ++j)
            acc += bA[j] * wnb[j] + bB[j] * wnb[j];
    }
    for (; i < re; ++i) {
        const int e = sorted[i];
        const int t = dst[e];
        const float4 xt = xyz[t];
        const float* b = bond + (long)e * NB;
        const float pbt = pb[(long)t * OC + lane];
        const float dx = xs.x - xt.x, dy = xs.y - xt.y, dz = xs.z - xt.z;
        const float d2 = dx * dx + dy * dy + dz * dz;
        const float inv = (d2 > 0.f) ? __builtin_amdgcn_rcpf(d2) : 1.0e4f;
        float a = (pa + pbt) * inv;
#pragma unroll
        for (int j = 0; j < NB; ++j) a += b[j] * wnb[j];
        acc += a;
    }
    out[(long)n * OC + lane] += acc;   // only write: no atomics anywhere
}

// ---------------------------------------------------------------------------
extern "C" void kernel_launch(void* const* d_in, const int* in_sizes, int n_in,
                              void* d_out, int out_size, void* d_ws, size_t ws_size,
                              hipStream_t stream) {
    const float* feat = (const float*)d_in[0];
    const float* bond = (const float*)d_in[1];
    const float* w_s  = (const float*)d_in[2];
    const float* w_n  = (const float*)d_in[3];
    const int*   src  = (const int*)d_in[4];
    const int*   dstv = (const int*)d_in[5];
    float* out = (float*)d_out;

    // workspace layout (all 16B-aligned), total ~31.6 MB
    char* base = (char*)d_ws;
    float*  pb     = (float*) (base);                         // 25,600,000 B
    float4* xyz    = (float4*)(base + 25600000);              //  1,600,000 B
    int*    row    = (int*)   (base + 27200000);              //    400,016 B
    int*    cnt    = (int*)   (base + 27600016);              //    400,000 B
    int*    cursor = (int*)   (base + 28000016);              //    400,000 B
    int*    sorted = (int*)   (base + 28400016);              //  3,200,000 B

    hipMemsetAsync(cnt, 0, N_NODES * sizeof(int), stream);

    k_node<<<1024, 256, 0, stream>>>(feat, w_s, out, xyz, 0);
    k_node<<<1024, 256, 0, stream>>>(feat, w_n, pb,  xyz, 1);

    k_hist   <<<(N_EDGES + 255) / 256, 256, 0, stream>>>(src, cnt);
    k_scan   <<<1, SCAN_T, 0, stream>>>(cnt, row, cursor);
    k_scatter<<<(N_EDGES + 255) / 256, 256, 0, stream>>>(src, cursor, sorted);

    k_gather <<<(N_NODES * 64 + 255) / 256, 256, 0, stream>>>(
        row, sorted, dstv, bond, w_n, pb, xyz, out);
}

// Round 4
// 500.935 us; speedup vs baseline: 1.4198x; 1.4198x over previous
//
#include <hip/hip_runtime.h>

#define N_NODES 100000
#define N_EDGES 800000
#define NF 81
#define NB 22
#define OC 64
#define SCAN_CHUNK 1024
#define SCAN_BLOCKS ((N_NODES + SCAN_CHUNK - 1) / SCAN_CHUNK)   // 98

// ---------------------------------------------------------------------------
// Node GEMM: outp[n,:] = feat[n,:81] @ w[:81,:64].
// Wave per node, lane = channel, weight column register-resident; feat row
// batch-loaded (s_load_dwordx batches, one wait) before the fmac chain.
__global__ __launch_bounds__(256) void k_node(
    const float* __restrict__ feat, const float* __restrict__ w,
    float* __restrict__ outp, float4* __restrict__ xyz, int write_xyz)
{
    const int lane = threadIdx.x & 63;
    const int wid  = (int)((blockIdx.x * blockDim.x + threadIdx.x) >> 6);
    const int nw   = (int)((gridDim.x * blockDim.x) >> 6);

    float wc[NF];
#pragma unroll
    for (int k = 0; k < NF; ++k) wc[k] = w[k * OC + lane];

    for (int n0 = wid; n0 < N_NODES; n0 += nw) {
        const int n = __builtin_amdgcn_readfirstlane(n0);
        const float* f = feat + (long)n * NF;
        float fr[NF];
#pragma unroll
        for (int k = 0; k < NF; ++k) fr[k] = f[k];
        float a0 = 0.f, a1 = 0.f;
#pragma unroll
        for (int k = 0; k + 1 < NF; k += 2) {
            a0 += fr[k] * wc[k];
            a1 += fr[k + 1] * wc[k + 1];
        }
        a0 += fr[NF - 1] * wc[NF - 1];
        outp[(long)n * OC + lane] = a0 + a1;
        if (write_xyz && lane == 0)
            xyz[n] = make_float4(fr[0], fr[1], fr[2], 0.f);
    }
}

// ---------------------------------------------------------------------------
// Counting sort by src: hist -> 3-phase parallel scan -> scatter.
__global__ void k_hist(const int* __restrict__ src, int* __restrict__ cnt) {
    const int e = blockIdx.x * blockDim.x + threadIdx.x;
    if (e < N_EDGES) atomicAdd(&cnt[src[e]], 1);
}

// Phase A: per-block (1024 counts) exclusive scan into row; block sum -> bsum.
__global__ __launch_bounds__(256) void k_scan_blk(
    const int* __restrict__ cnt, int* __restrict__ row, int* __restrict__ bsum)
{
    __shared__ int sh[256];
    const int t = threadIdx.x;
    const int base = blockIdx.x * SCAN_CHUNK + t * 4;
    int c0 = 0, c1 = 0, c2 = 0, c3 = 0;
    if (base + 3 < N_NODES) {
        const int4 c = *(const int4*)(cnt + base);
        c0 = c.x; c1 = c.y; c2 = c.z; c3 = c.w;
    } else {
        if (base + 0 < N_NODES) c0 = cnt[base + 0];
        if (base + 1 < N_NODES) c1 = cnt[base + 1];
        if (base + 2 < N_NODES) c2 = cnt[base + 2];
        if (base + 3 < N_NODES) c3 = cnt[base + 3];
    }
    const int s = c0 + c1 + c2 + c3;
    sh[t] = s;
    __syncthreads();
    for (int off = 1; off < 256; off <<= 1) {   // Hillis-Steele inclusive
        int v = sh[t];
        int a = (t >= off) ? sh[t - off] : 0;
        __syncthreads();
        sh[t] = v + a;
        __syncthreads();
    }
    const int excl = sh[t] - s;
    if (t == 255) bsum[blockIdx.x] = sh[255];
    if (base + 3 < N_NODES) {
        int4 r;
        r.x = excl; r.y = excl + c0; r.z = excl + c0 + c1; r.w = excl + c0 + c1 + c2;
        *(int4*)(row + base) = r;
    } else {
        int e = excl;
        if (base + 0 < N_NODES) { row[base + 0] = e; e += c0; }
        if (base + 1 < N_NODES) { row[base + 1] = e; e += c1; }
        if (base + 2 < N_NODES) { row[base + 2] = e; }
    }
}

// Phase B: scan the 98 block sums (one tiny block); also writes row[N_NODES].
__global__ void k_scan_top(int* __restrict__ bsum, int* __restrict__ row) {
    __shared__ int sh[128];
    const int t = threadIdx.x;
    const int v = (t < SCAN_BLOCKS) ? bsum[t] : 0;
    sh[t] = v;
    __syncthreads();
    for (int off = 1; off < 128; off <<= 1) {
        int x = sh[t];
        int a = (t >= off) ? sh[t - off] : 0;
        __syncthreads();
        sh[t] = x + a;
        __syncthreads();
    }
    if (t < SCAN_BLOCKS) bsum[t] = sh[t] - v;       // exclusive, in place
    if (t == 127) row[N_NODES] = sh[127];           // total = N_EDGES
}

// Phase C: add block offsets; duplicate into cursor for the scatter.
__global__ __launch_bounds__(256) void k_scan_add(
    int* __restrict__ row, int* __restrict__ cursor, const int* __restrict__ bsum)
{
    const int off = bsum[blockIdx.x];
    const int base = blockIdx.x * SCAN_CHUNK + threadIdx.x * 4;
    if (base + 3 < N_NODES) {
        int4 r = *(const int4*)(row + base);
        r.x += off; r.y += off; r.z += off; r.w += off;
        *(int4*)(row + base) = r;
        *(int4*)(cursor + base) = r;
    } else {
#pragma unroll
        for (int k = 0; k < 4; ++k)
            if (base + k < N_NODES) {
                const int v = row[base + k] + off;
                row[base + k] = v;
                cursor[base + k] = v;
            }
    }
}

__global__ void k_scatter(const int* __restrict__ src, int* __restrict__ cursor,
                          int* __restrict__ sorted) {
    const int e = blockIdx.x * blockDim.x + threadIdx.x;
    if (e < N_EDGES) {
        const int pos = atomicAdd(&cursor[src[e]], 1);
        sorted[pos] = e;
    }
}

// ---------------------------------------------------------------------------
// Gather: wave per node, lane = channel, NO atomics. 4 edges per iteration
// (avg degree 8 -> 2 memory rounds/node); all 4 edges' loads issue as one
// batch (sorted/dst/bond on the scalar pipe, pb/xyz on the vector pipe).
__global__ __launch_bounds__(256) void k_gather(
    const int* __restrict__ row, const int* __restrict__ sorted,
    const int* __restrict__ dst, const float* __restrict__ bond,
    const float* __restrict__ w_n, const float* __restrict__ pb,
    const float4* __restrict__ xyz, float* __restrict__ out)
{
    const int lane = threadIdx.x & 63;
    const int wid  = (int)((blockIdx.x * blockDim.x + threadIdx.x) >> 6);
    if (wid >= N_NODES) return;
    const int n = __builtin_amdgcn_readfirstlane(wid);

    float wnb[NB];
#pragma unroll
    for (int j = 0; j < NB; ++j) wnb[j] = w_n[(NF + j) * OC + lane];
    const float w0 = w_n[0 * OC + lane];
    const float w1 = w_n[1 * OC + lane];
    const float w2 = w_n[2 * OC + lane];

    const int rs = row[n], re = row[n + 1];
    const float4 xs = xyz[n];
    const float pa = pb[(long)n * OC + lane]
                   - (xs.x * w0 + xs.y * w1 + xs.z * w2);

    float acc = 0.f;
    int i = rs;
    for (; i + 4 <= re; i += 4) {
        const int eA = sorted[i],     eB = sorted[i + 1];
        const int eC = sorted[i + 2], eD = sorted[i + 3];
        const int tA = dst[eA], tB = dst[eB], tC = dst[eC], tD = dst[eD];
        const float4 xtA = xyz[tA], xtB = xyz[tB], xtC = xyz[tC], xtD = xyz[tD];
        const float pbtA = pb[(long)tA * OC + lane];
        const float pbtB = pb[(long)tB * OC + lane];
        const float pbtC = pb[(long)tC * OC + lane];
        const float pbtD = pb[(long)tD * OC + lane];
        const float* bA = bond + (long)eA * NB;
        const float* bB = bond + (long)eB * NB;
        const float* bC = bond + (long)eC * NB;
        const float* bD = bond + (long)eD * NB;

        float dx, dy, dz;
        dx = xs.x - xtA.x; dy = xs.y - xtA.y; dz = xs.z - xtA.z;
        const float d2A = dx * dx + dy * dy + dz * dz;
        dx = xs.x - xtB.x; dy = xs.y - xtB.y; dz = xs.z - xtB.z;
        const float d2B = dx * dx + dy * dy + dz * dz;
        dx = xs.x - xtC.x; dy = xs.y - xtC.y; dz = xs.z - xtC.z;
        const float d2C = dx * dx + dy * dy + dz * dz;
        dx = xs.x - xtD.x; dy = xs.y - xtD.y; dz = xs.z - xtD.z;
        const float d2D = dx * dx + dy * dy + dz * dz;
        const float invA = (d2A > 0.f) ? __builtin_amdgcn_rcpf(d2A) : 1.0e4f;
        const float invB = (d2B > 0.f) ? __builtin_amdgcn_rcpf(d2B) : 1.0e4f;
        const float invC = (d2C > 0.f) ? __builtin_amdgcn_rcpf(d2C) : 1.0e4f;
        const float invD = (d2D > 0.f) ? __builtin_amdgcn_rcpf(d2D) : 1.0e4f;

        acc += (pa + pbtA) * invA + (pa + pbtB) * invB
             + (pa + pbtC) * invC + (pa + pbtD) * invD;
#pragma unroll
        for (int j = 0; j < NB; ++j)
            acc += bA[j] * wnb[j] + bB[j] * wnb[j]
                 + bC[j] * wnb[j] + bD[j] * wnb[j];
    }
    for (; i < re; ++i) {
        const int e = sorted[i];
        const int t = dst[e];
        const float4 xt = xyz[t];
        const float* b = bond + (long)e * NB;
        const float pbt = pb[(long)t * OC + lane];
        const float dx = xs.x - xt.x, dy = xs.y - xt.y, dz = xs.z - xt.z;
        const float d2 = dx * dx + dy * dy + dz * dz;
        const float inv = (d2 > 0.f) ? __builtin_amdgcn_rcpf(d2) : 1.0e4f;
        float a = (pa + pbt) * inv;
#pragma unroll
        for (int j = 0; j < NB; ++j) a += b[j] * wnb[j];
        acc += a;
    }
    out[(long)n * OC + lane] += acc;
}

// ---------------------------------------------------------------------------
extern "C" void kernel_launch(void* const* d_in, const int* in_sizes, int n_in,
                              void* d_out, int out_size, void* d_ws, size_t ws_size,
                              hipStream_t stream) {
    const float* feat = (const float*)d_in[0];
    const float* bond = (const float*)d_in[1];
    const float* w_s  = (const float*)d_in[2];
    const float* w_n  = (const float*)d_in[3];
    const int*   src  = (const int*)d_in[4];
    const int*   dstv = (const int*)d_in[5];
    float* out = (float*)d_out;

    // workspace layout (16B-aligned), total ~31.6 MB
    char* base = (char*)d_ws;
    float*  pb     = (float*) (base);                   // 25,600,000 B
    float4* xyz    = (float4*)(base + 25600000);        //  1,600,000 B
    int*    row    = (int*)   (base + 27200000);        //    400,016 B
    int*    cnt    = (int*)   (base + 27600016);        //    400,000 B
    int*    cursor = (int*)   (base + 28000016);        //    400,000 B
    int*    sorted = (int*)   (base + 28400016);        //  3,200,000 B
    int*    bsum   = (int*)   (base + 31600016);        //        512 B

    hipMemsetAsync(cnt, 0, N_NODES * sizeof(int), stream);

    k_node<<<1024, 256, 0, stream>>>(feat, w_s, out, xyz, 0);
    k_node<<<1024, 256, 0, stream>>>(feat, w_n, pb,  xyz, 1);

    k_hist    <<<(N_EDGES + 255) / 256, 256, 0, stream>>>(src, cnt);
    k_scan_blk<<<SCAN_BLOCKS, 256, 0, stream>>>(cnt, row, bsum);
    k_scan_top<<<1, 128, 0, stream>>>(bsum, row);
    k_scan_add<<<SCAN_BLOCKS, 256, 0, stream>>>(row, cursor, bsum);
    k_scatter <<<(N_EDGES + 255) / 256, 256, 0, stream>>>(src, cursor, sorted);

    k_gather  <<<(N_NODES * 64 + 255) / 256, 256, 0, stream>>>(
        row, sorted, dstv, bond, w_n, pb, xyz, out);
}